// Round 9
// baseline (327.837 us; speedup 1.0000x reference)
//
#include <hip/hip_runtime.h>

// MSDeformAttn — R13: depth-2 gather pipeline, now inside a no-spill budget.
//  R12 confirmed both theories: samp2 VGPR=48 (no spill; register-split law:
//  cap 102 -> 48 arch + 8 AGPR), WRITE 150->65MB, dur 147->118us.
//  Remaining: VALUBusy 45%, HBM 21%, occ 46% — still gather-latency-bound.
//  Service arithmetic: 22.3M distinct 64B lines => ~36us TA floor; we're 3.3x
//  over => too few outstanding misses/CU. R8's depth-2 pipeline failed ONLY by
//  spill (mega held 24 AGPR: 80 arch + 24 > 102). samp2 holds 8 AGPR:
//  80 + 8 = 88 <= 102 — fits. R13 = R12 + depth-2 ISSUE/ACCUM sampler
//  (8 outstanding 16B gathers/thread). Abort: VGPR<=56 + WRITE>100MB = spill.
// B=2, C=256, nH=8, nL=4, nP=4, hd=32, Len=21760.
// Shapes compile-time: [[128,128],[64,64],[32,32],[16,16]], starts [0,16384,20480,21504].

#define NH 8
#define NL 4
#define NP 4
#define CDIM 256
#define HD 32
#define QB 16
#define QSTR 264   // fallback kernel only
#define ASTR 132   // fallback kernel only
// bank swizzle for packed chunk layouts (involution; keyed on bits 4-6)
#define SWZ(c) ((c) ^ ((((c) >> 4)) & 7))

typedef short bf16x8 __attribute__((ext_vector_type(8)));
typedef float f32x4  __attribute__((ext_vector_type(4)));
typedef _Float16 f16x8v __attribute__((ext_vector_type(8)));
typedef _Float16 f16x4v __attribute__((ext_vector_type(4)));
typedef _Float16 f16x2v __attribute__((ext_vector_type(2)));

#define SPLAT8(x) (f16x8v){(x),(x),(x),(x),(x),(x),(x),(x)}

__device__ __forceinline__ short f2bf(float x) {
    union { float f; unsigned u; } v; v.f = x;
    const unsigned r = v.u + 0x7FFFu + ((v.u >> 16) & 1u);
    return (short)(r >> 16);
}

__constant__ int LVL_S_C[4] = {0, 16384, 20480, 21504};

// ---- convert: weights (blocks [0,640)) + features f16 (blocks [640,...)) ----
__global__ __launch_bounds__(256) void convert_all(
    const float* __restrict__ W_off, const float* __restrict__ W_attn,
    const float* __restrict__ W_out, const float* __restrict__ feat,
    short* __restrict__ wt, _Float16* __restrict__ fh, int n4)
{
    const int bid = blockIdx.x;
    if (bid < 640) {
        const int gid = bid * 256 + threadIdx.x;
        if (gid < 65536) {
            const int c = gid >> 8, k = gid & 255;
            wt[gid] = f2bf(W_off[k * 256 + c]);
        } else if (gid < 98304) {
            const int g = gid - 65536, c = g >> 8, k = g & 255;
            wt[gid] = f2bf(W_attn[k * 128 + c]);
        } else if (gid < 163840) {
            const int g = gid - 98304, c = g >> 8, k = g & 255;
            wt[gid] = f2bf(W_out[k * 256 + c]);
        }
    } else {
        const int gid = (bid - 640) * 256 + threadIdx.x;
        if (gid < n4) {
            const float4 v = *(const float4*)&feat[gid * 4];
            f16x4v o;
            o[0] = (_Float16)v.x; o[1] = (_Float16)v.y;
            o[2] = (_Float16)v.z; o[3] = (_Float16)v.w;
            *(f16x4v*)&fh[gid * 4] = o;
        }
    }
}

// ---- kernel B: GEMM1 (MFMA) + softmax; offs/aw (f16) -> out-buffer scratch ----
// scratch layout per global row g (bytes, inside out): [g*1024 + 0, +512) offs
//   f16 [pi*16 + h*2 + xy]; [g*1024 + 512, +768) aw f16 [h*16 + pi].
__global__ __launch_bounds__(256, 4) void msda_gemm1(
    const float* __restrict__ query, const short* __restrict__ wt,
    const float* __restrict__ b_off, const float* __restrict__ b_attn,
    char* __restrict__ scr)
{
    const int t = threadIdx.x;
    const int lane = t & 63;
    const int wave = t >> 6;
    const int qr = lane & 15;
    const int quad = lane >> 4;
    const long long qbase = (long long)blockIdx.x * QB;

    // union (8192 B): qp (bf16, packed lane-linear, SWZ) then offs f16 [i][pi*16+h*2+xy]
    __shared__ __align__(16) short uni[QB * CDIM];
    short* qp = uni;
    _Float16* offs16 = (_Float16*)uni;
    __shared__ __align__(16) _Float16 aw_lds[QB * 128];   // [i][h*16+pi], 4096 B
    // total 12288 B

    // ---- stage query (fp32 -> bf16, packed: chunk = (k>>5)*64 + ((k>>3)&3)*16 + i) ----
    #pragma unroll
    for (int it = 0; it < 4; ++it) {
        const int e = it * 1024 + t * 4;
        const int i = e >> 8, k = e & 255;
        const float4 v = *(const float4*)&query[(qbase + i) * CDIM + k];
        const int chunk = (k >> 5) * 64 + ((k >> 3) & 3) * 16 + i;
        short4 o;
        o.x = f2bf(v.x); o.y = f2bf(v.y); o.z = f2bf(v.z); o.w = f2bf(v.w);
        *(short4*)&qp[SWZ(chunk) * 8 + (k & 7)] = o;
    }
    __syncthreads();

    const short* __restrict__ Wt_off  = wt;
    const short* __restrict__ Wt_attn = wt + 65536;

    {
        f32x4 acc[4], acca[2];
        #pragma unroll
        for (int j = 0; j < 4; ++j) acc[j] = (f32x4){0.f, 0.f, 0.f, 0.f};
        #pragma unroll
        for (int j = 0; j < 2; ++j) acca[j] = (f32x4){0.f, 0.f, 0.f, 0.f};

        const short* bb_off  = Wt_off  + qr * 256 + quad * 8;
        const short* bb_attn = Wt_attn + qr * 256 + quad * 8;
        #pragma unroll
        for (int s = 0; s < 8; ++s) {
            const bf16x8 af = *(const bf16x8*)&qp[SWZ(s * 64 + lane) * 8];  // conflict-free
            #pragma unroll
            for (int j = 0; j < 4; ++j) {
                const bf16x8 bf = *(const bf16x8*)(bb_off + ((j * 4 + wave) * 16) * 256 + s * 32);
                acc[j] = __builtin_amdgcn_mfma_f32_16x16x32_bf16(af, bf, acc[j], 0, 0, 0);
            }
            #pragma unroll
            for (int j = 0; j < 2; ++j) {
                const bf16x8 bf = *(const bf16x8*)(bb_attn + ((j * 4 + wave) * 16) * 256 + s * 32);
                acca[j] = __builtin_amdgcn_mfma_f32_16x16x32_bf16(af, bf, acca[j], 0, 0, 0);
            }
        }
        __syncthreads();   // all qp reads done; union becomes offs16

        // D layout: col = qr, row = quad*4 + r.
        #pragma unroll
        for (int j = 0; j < 4; ++j) {
            const int col = (j * 4 + wave) * 16 + qr;
            const float bo = b_off[col];
            const int h = col >> 5, rem = col & 31;   // rem = pi*2 + xy
            const int pos = (rem >> 1) * 16 + (h << 1) + (rem & 1);
            #pragma unroll
            for (int r = 0; r < 4; ++r)
                offs16[(quad * 4 + r) * 256 + pos] = (_Float16)(acc[j][r] + bo);
        }
        #pragma unroll
        for (int j = 0; j < 2; ++j) {
            const int col = (j * 4 + wave) * 16 + qr;
            const float ba = b_attn[col];
            const int h = col >> 4;                   // pi = col & 15 = qr
            #pragma unroll
            for (int r = 0; r < 4; ++r)
                aw_lds[(quad * 4 + r) * 128 + (h << 4) + qr] = (_Float16)(acca[j][r] + ba);
        }
    }
    __syncthreads();

    // ---- softmax per (row, head), 128 threads, vectorized f16x8 ----
    if (t < QB * NH) {
        const int i = t >> 3, h = t & 7;
        _Float16* row = &aw_lds[i * 128 + (h << 4)];
        f16x8v v0 = *(const f16x8v*)row;
        f16x8v v1 = *(const f16x8v*)(row + 8);
        float vals[16], mx = -1e30f;
        #pragma unroll
        for (int j = 0; j < 8; ++j) { vals[j] = (float)v0[j]; vals[8 + j] = (float)v1[j]; }
        #pragma unroll
        for (int j = 0; j < 16; ++j) mx = fmaxf(mx, vals[j]);
        float s = 0.f;
        #pragma unroll
        for (int j = 0; j < 16; ++j) { vals[j] = __expf(vals[j] - mx); s += vals[j]; }
        const float inv = 1.f / s;
        #pragma unroll
        for (int j = 0; j < 8; ++j) { v0[j] = (_Float16)(vals[j] * inv); v1[j] = (_Float16)(vals[8 + j] * inv); }
        *(f16x8v*)row = v0;
        *(f16x8v*)(row + 8) = v1;
    }
    __syncthreads();

    // ---- bulk copy LDS -> out-scratch (16B chunks, coalesced) ----
    // offs: 16 rows x 512 B = 512 chunks; aw: 16 rows x 256 B = 256 chunks
    #pragma unroll
    for (int it = 0; it < 2; ++it) {
        const int chunk = it * 256 + t;
        const int row = chunk >> 5, c = chunk & 31;
        const bf16x8 v = *(const bf16x8*)&uni[chunk * 8];
        *(bf16x8*)(scr + (qbase + row) * 1024 + c * 16) = v;
    }
    {
        const int row = t >> 4, c = t & 15;
        const bf16x8 v = *(const bf16x8*)&((short*)aw_lds)[t * 8];
        *(bf16x8*)(scr + (qbase + row) * 1024 + 512 + c * 16) = v;
    }
}

// ---- kernel C: stage offs/aw -> LDS, depth-2 pipelined sampler, GEMM2 -> out ----
__global__ __launch_bounds__(256, 5) void msda_samp2(
    const float* __restrict__ ref_pts, const _Float16* __restrict__ feath,
    const short* __restrict__ wt, const float* __restrict__ b_out,
    float* __restrict__ out, int Len)
{
    const int t = threadIdx.x;
    const int lane = t & 63;
    const int wave = t >> 6;
    const int qr = lane & 15;
    const int quad = lane >> 4;

    // ---- bijective XCD swizzle: consecutive final blocks share an XCD's L2.
    int bid;
    {
        const int nwg = gridDim.x, orig = blockIdx.x;
        const int q = nwg >> 3, r = nwg & 7;
        const int xcd = orig & 7, idx = orig >> 3;
        bid = (xcd < r ? xcd * (q + 1) : r * (q + 1) + (xcd - r) * q) + idx;
    }
    const long long qbase = (long long)bid * QB;
    const int b = (int)(qbase / Len);   // Len % QB == 0, no crossing

    // sc: row i at shorts [i*384, i*384+384): offs [0,256), aw [256,384)  (12288 B)
    __shared__ __align__(16) short sc[QB * 384];
    __shared__ __align__(16) short pre_lds[QB * CDIM];  // 8192 B, packed lane-linear, SWZ
    // total 20480 B; (256,5): cap 102 unified. Depth-2 needs ~80 arch + 8 AGPR
    // = 88 <= 102 (R8's spill was mega's 24 AGPR pushing this to 104).

    const int rl = t >> 5;
    const float rx0 = ref_pts[(qbase + rl) * 2];
    const float ry0 = ref_pts[(qbase + rl) * 2 + 1];
    const float rx1 = ref_pts[(qbase + 8 + rl) * 2];
    const float ry1 = ref_pts[(qbase + 8 + rl) * 2 + 1];

    // ---- stage scratch rows: 16 rows x 768 B = 768 16B-chunks, 3 iters ----
    const char* scr = (const char*)out;
    #pragma unroll
    for (int it = 0; it < 3; ++it) {
        const int chunk = it * 256 + t;
        const int row = chunk / 48, c = chunk - row * 48;
        const bf16x8 v = *(const bf16x8*)(scr + (qbase + row) * 1024 + c * 16);
        *(bf16x8*)&sc[row * 384 + c * 8] = v;
    }
    __syncthreads();

    // ---- sampling: 2 passes x 8 rows; 32 lanes/row (h = l32>>2, ct = l32&3);
    //      depth-2 software pipeline: 8 outstanding 16B gathers/thread ----
    {
        const int l32 = t & 31;
        const int h = l32 >> 2, ct = l32 & 3;
        const int c0 = h * HD + ct * 8;
        #pragma unroll 1
        for (int pass = 0; pass < 2; ++pass) {
            const int i = pass * 8 + rl;
            const float rx = pass ? rx1 : rx0;
            const float ry = pass ? ry1 : ry0;
            const _Float16* __restrict__ offr = (const _Float16*)&sc[i * 384] + h * 2;
            const _Float16* __restrict__ awr  = (const _Float16*)&sc[i * 384 + 256] + h * 16;
            float acc[8];
            #pragma unroll
            for (int c = 0; c < 8; ++c) acc[c] = 0.f;
            f16x8v pA0, pA1, pA2, pA3, pB0, pB1, pB2, pB3;
            float qA0, qA1, qA2, qA3, qB0, qB1, qB2, qB3;

#define MSDA_ISSUE(pi, P0, P1, P2, P3, Q0, Q1, Q2, Q3) do {                         \
            const int l_ = (pi) >> 2;                                               \
            const int Wl_ = 128 >> l_;                                              \
            const int base_ = (b * Len + LVL_S_C[l_]) * CDIM + c0;                  \
            const f16x2v oxy_ = *(const f16x2v*)(offr + (pi) * 16);                 \
            const float a_ = (float)awr[(pi)];                                      \
            const float x_ = fmaf(rx, (float)Wl_, (float)oxy_[0]) - 0.5f;           \
            const float y_ = fmaf(ry, (float)Wl_, (float)oxy_[1]) - 0.5f;           \
            const float xf_ = floorf(x_), yf_ = floorf(y_);                         \
            const int x0_ = (int)xf_, y0_ = (int)yf_;                               \
            const float wx_ = x_ - xf_, wy_ = y_ - yf_;                             \
            const float ax0_ = ((unsigned)x0_       < (unsigned)Wl_) ? (1.f - wx_) : 0.f; \
            const float ax1_ = ((unsigned)(x0_ + 1) < (unsigned)Wl_) ? wx_         : 0.f; \
            const float ay0_ = (((unsigned)y0_       < (unsigned)Wl_) ? (1.f - wy_) : 0.f) * a_; \
            const float ay1_ = (((unsigned)(y0_ + 1) < (unsigned)Wl_) ? wy_         : 0.f) * a_; \
            const int x0c_ = min(max(x0_, 0), Wl_ - 1), x1c_ = min(max(x0_ + 1, 0), Wl_ - 1); \
            const int y0c_ = min(max(y0_, 0), Wl_ - 1), y1c_ = min(max(y0_ + 1, 0), Wl_ - 1); \
            P0 = *(const f16x8v*)(feath + base_ + (y0c_ * Wl_ + x0c_) * CDIM);      \
            P1 = *(const f16x8v*)(feath + base_ + (y0c_ * Wl_ + x1c_) * CDIM);      \
            P2 = *(const f16x8v*)(feath + base_ + (y1c_ * Wl_ + x0c_) * CDIM);      \
            P3 = *(const f16x8v*)(feath + base_ + (y1c_ * Wl_ + x1c_) * CDIM);      \
            Q0 = ax0_ * ay0_; Q1 = ax1_ * ay0_;                                     \
            Q2 = ax0_ * ay1_; Q3 = ax1_ * ay1_; } while (0)

#define MSDA_ACCUM(P0, P1, P2, P3, Q0, Q1, Q2, Q3) do {                             \
            f16x8v bil_ = P0 * SPLAT8((_Float16)Q0);                                \
            bil_ += P1 * SPLAT8((_Float16)Q1);                                      \
            bil_ += P2 * SPLAT8((_Float16)Q2);                                      \
            bil_ += P3 * SPLAT8((_Float16)Q3);                                      \
            _Pragma("unroll")                                                       \
            for (int c_ = 0; c_ < 8; ++c_) acc[c_] += (float)bil_[c_]; } while (0)

            MSDA_ISSUE(0, pA0, pA1, pA2, pA3, qA0, qA1, qA2, qA3);
            MSDA_ISSUE(1, pB0, pB1, pB2, pB3, qB0, qB1, qB2, qB3);
            #pragma unroll
            for (int pi = 2; pi < 16; pi += 2) {
                MSDA_ACCUM(pA0, pA1, pA2, pA3, qA0, qA1, qA2, qA3);
                MSDA_ISSUE(pi, pA0, pA1, pA2, pA3, qA0, qA1, qA2, qA3);
                MSDA_ACCUM(pB0, pB1, pB2, pB3, qB0, qB1, qB2, qB3);
                MSDA_ISSUE(pi + 1, pB0, pB1, pB2, pB3, qB0, qB1, qB2, qB3);
            }
            MSDA_ACCUM(pA0, pA1, pA2, pA3, qA0, qA1, qA2, qA3);   // pi = 14
            MSDA_ACCUM(pB0, pB1, pB2, pB3, qB0, qB1, qB2, qB3);   // pi = 15
#undef MSDA_ISSUE
#undef MSDA_ACCUM

            bf16x8 pv;
            #pragma unroll
            for (int c = 0; c < 8; ++c) pv[c] = f2bf(acc[c]);
            // packed lane-linear: chunk = h*64 + ct*16 + i
            *(bf16x8*)&pre_lds[SWZ(h * 64 + ct * 16 + i) * 8] = pv;
        }
    }
    __syncthreads();

    // ---- GEMM2: out = pre @ W_out + b_out; j-loop halved => 8 acc regs peak ----
    {
        const short* bb = wt + 98304 + qr * 256 + quad * 8;
        #pragma unroll 1
        for (int half = 0; half < 2; ++half) {
            f32x4 acc[2];
            #pragma unroll
            for (int j = 0; j < 2; ++j) acc[j] = (f32x4){0.f, 0.f, 0.f, 0.f};
            #pragma unroll
            for (int s = 0; s < 8; ++s) {
                const bf16x8 af = *(const bf16x8*)&pre_lds[SWZ(s * 64 + lane) * 8];
                #pragma unroll
                for (int j = 0; j < 2; ++j) {
                    const int jj = half * 2 + j;
                    const bf16x8 bf = *(const bf16x8*)(bb + ((jj * 4 + wave) * 16) * 256 + s * 32);
                    acc[j] = __builtin_amdgcn_mfma_f32_16x16x32_bf16(af, bf, acc[j], 0, 0, 0);
                }
            }
            #pragma unroll
            for (int j = 0; j < 2; ++j) {
                const int col = ((half * 2 + j) * 4 + wave) * 16 + qr;
                const float bo = b_out[col];
                #pragma unroll
                for (int r = 0; r < 4; ++r)
                    out[(qbase + quad * 4 + r) * CDIM + col] = acc[j][r] + bo;
            }
        }
    }
}

// ---- fallback: fused kernel, fp32 features (ws too small) ----
__global__ __launch_bounds__(256) void msda_fused_fb(
    const float* __restrict__ query, const float* __restrict__ ref_pts,
    const float* __restrict__ feat_f32, const short* __restrict__ wt,
    const float* __restrict__ b_off, const float* __restrict__ b_attn,
    const float* __restrict__ b_out, float* __restrict__ out, int Len)
{
    const int t = threadIdx.x;
    const int lane = t & 63;
    const int wave = t >> 6;
    const int qr = lane & 15;
    const int quad = lane >> 4;
    const long long qbase = (long long)blockIdx.x * QB;
    const int b = (int)(qbase / Len);

    __shared__ __align__(16) char uni[QB * QSTR * 4];
    short* qp = (short*)uni;
    float* offs_lds = (float*)uni;
    __shared__ float aw_lds[QB * ASTR];
    __shared__ __align__(16) short pre_lds[QB * QSTR];
    __shared__ float ref_sm[QB][2];

    #pragma unroll
    for (int it = 0; it < 4; ++it) {
        const int e = it * 1024 + t * 4;
        const int i = e >> 8, k = e & 255;
        const float4 v = *(const float4*)&query[(qbase + i) * CDIM + k];
        short4 o;
        o.x = f2bf(v.x); o.y = f2bf(v.y); o.z = f2bf(v.z); o.w = f2bf(v.w);
        *(short4*)&qp[i * QSTR + k] = o;
    }
    if (t < QB * 2) ref_sm[t >> 1][t & 1] = ref_pts[(qbase + (t >> 1)) * 2 + (t & 1)];
    __syncthreads();

    const short* __restrict__ Wt_off  = wt;
    const short* __restrict__ Wt_attn = wt + 65536;
    const short* __restrict__ Wt_out  = wt + 98304;

    {
        f32x4 acc[4], acca[2];
        #pragma unroll
        for (int j = 0; j < 4; ++j) acc[j] = (f32x4){0.f, 0.f, 0.f, 0.f};
        #pragma unroll
        for (int j = 0; j < 2; ++j) acca[j] = (f32x4){0.f, 0.f, 0.f, 0.f};
        const short* bb_off  = Wt_off  + qr * 256 + quad * 8;
        const short* bb_attn = Wt_attn + qr * 256 + quad * 8;
        #pragma unroll
        for (int s = 0; s < 8; ++s) {
            const bf16x8 af = *(const bf16x8*)&qp[qr * QSTR + s * 32 + quad * 8];
            #pragma unroll
            for (int j = 0; j < 4; ++j) {
                const bf16x8 bf = *(const bf16x8*)(bb_off + ((j * 4 + wave) * 16) * 256 + s * 32);
                acc[j] = __builtin_amdgcn_mfma_f32_16x16x32_bf16(af, bf, acc[j], 0, 0, 0);
            }
            #pragma unroll
            for (int j = 0; j < 2; ++j) {
                const bf16x8 bf = *(const bf16x8*)(bb_attn + ((j * 4 + wave) * 16) * 256 + s * 32);
                acca[j] = __builtin_amdgcn_mfma_f32_16x16x32_bf16(af, bf, acca[j], 0, 0, 0);
            }
        }
        __syncthreads();
        #pragma unroll
        for (int j = 0; j < 4; ++j) {
            const int col = (j * 4 + wave) * 16 + qr;
            const float bo = b_off[col];
            const int h = col >> 5, rem = col & 31;
            #pragma unroll
            for (int r = 0; r < 4; ++r)
                offs_lds[(quad * 4 + r) * QSTR + rem * 8 + h] = acc[j][r] + bo;
        }
        #pragma unroll
        for (int j = 0; j < 2; ++j) {
            const int col = (j * 4 + wave) * 16 + qr;
            const float ba = b_attn[col];
            const int h = col >> 4, rem = col & 15;
            #pragma unroll
            for (int r = 0; r < 4; ++r)
                aw_lds[(quad * 4 + r) * ASTR + rem * 8 + h] = acca[j][r] + ba;
        }
    }
    __syncthreads();

    if (t < QB * NH) {
        const int i = t >> 3, h = t & 7;
        float* row = &aw_lds[i * ASTR];
        float vals[16], mx = -1e30f;
        #pragma unroll
        for (int j = 0; j < 16; ++j) { vals[j] = row[j * 8 + h]; mx = fmaxf(mx, vals[j]); }
        float s = 0.f;
        #pragma unroll
        for (int j = 0; j < 16; ++j) { vals[j] = __expf(vals[j] - mx); s += vals[j]; }
        const float inv = 1.f / s;
        #pragma unroll
        for (int j = 0; j < 16; ++j) row[j * 8 + h] = vals[j] * inv;
    }
    __syncthreads();

    {
        const int rl = t >> 5;
        const int l32 = t & 31;
        const int h = l32 >> 2, ct = l32 & 3;
        const int c0 = h * HD + ct * 8;
        #pragma unroll 1
        for (int pass = 0; pass < 2; ++pass) {
            const int i = pass * 8 + rl;
            const float rx = ref_sm[i][0], ry = ref_sm[i][1];
            const float* __restrict__ offr = &offs_lds[i * QSTR];
            const float* __restrict__ awr  = &aw_lds[i * ASTR];
            float acc[8];
            #pragma unroll
            for (int c = 0; c < 8; ++c) acc[c] = 0.f;
            #pragma unroll
            for (int l = 0; l < NL; ++l) {
                const int Wl = 128 >> l;
                const int base = (b * Len + LVL_S_C[l]) * CDIM + c0;
                #pragma unroll 2
                for (int p = 0; p < NP; ++p) {
                    const int pi = l * 4 + p;
                    const float ox = offr[pi * 16 + h];
                    const float oy = offr[pi * 16 + 8 + h];
                    const float a  = awr[pi * 8 + h];
                    const float x = fmaf(rx, (float)Wl, ox) - 0.5f;
                    const float y = fmaf(ry, (float)Wl, oy) - 0.5f;
                    const float xf = floorf(x), yf = floorf(y);
                    const int x0 = (int)xf, y0 = (int)yf;
                    const float wx = x - xf, wy = y - yf;
                    const float ax0 = ((unsigned)x0       < (unsigned)Wl) ? (1.f - wx) : 0.f;
                    const float ax1 = ((unsigned)(x0 + 1) < (unsigned)Wl) ? wx         : 0.f;
                    const float ay0 = (((unsigned)y0       < (unsigned)Wl) ? (1.f - wy) : 0.f) * a;
                    const float ay1 = (((unsigned)(y0 + 1) < (unsigned)Wl) ? wy         : 0.f) * a;
                    const int x0c = min(max(x0, 0), Wl - 1), x1c = min(max(x0 + 1, 0), Wl - 1);
                    const int y0c = min(max(y0, 0), Wl - 1), y1c = min(max(y0 + 1, 0), Wl - 1);
                    const float w00 = ax0 * ay0, w01 = ax1 * ay0;
                    const float w10 = ax0 * ay1, w11 = ax1 * ay1;
                    const int r0 = base + (y0c * Wl + x0c) * CDIM;
                    const int r1 = base + (y0c * Wl + x1c) * CDIM;
                    const int r2 = base + (y1c * Wl + x0c) * CDIM;
                    const int r3 = base + (y1c * Wl + x1c) * CDIM;
                    f32x4 a0 = *(const f32x4*)(feat_f32 + r0);
                    f32x4 a1 = *(const f32x4*)(feat_f32 + r0 + 4);
                    f32x4 b0 = *(const f32x4*)(feat_f32 + r1);
                    f32x4 b1 = *(const f32x4*)(feat_f32 + r1 + 4);
                    f32x4 c0v = *(const f32x4*)(feat_f32 + r2);
                    f32x4 c1 = *(const f32x4*)(feat_f32 + r2 + 4);
                    f32x4 d0 = *(const f32x4*)(feat_f32 + r3);
                    f32x4 d1 = *(const f32x4*)(feat_f32 + r3 + 4);
                    #pragma unroll
                    for (int c = 0; c < 4; ++c) {
                        acc[c]     += w00*a0[c] + w01*b0[c] + w10*c0v[c] + w11*d0[c];
                        acc[c + 4] += w00*a1[c] + w01*b1[c] + w10*c1[c]  + w11*d1[c];
                    }
                }
            }
            bf16x8 pv;
            #pragma unroll
            for (int c = 0; c < 8; ++c) pv[c] = f2bf(acc[c]);
            *(bf16x8*)&pre_lds[i * QSTR + c0] = pv;
        }
    }
    __syncthreads();

    {
        f32x4 acc[4];
        #pragma unroll
        for (int j = 0; j < 4; ++j) acc[j] = (f32x4){0.f, 0.f, 0.f, 0.f};
        const short* bb = Wt_out + qr * 256 + quad * 8;
        #pragma unroll
        for (int s = 0; s < 8; ++s) {
            const bf16x8 af = *(const bf16x8*)&pre_lds[qr * QSTR + s * 32 + quad * 8];
            #pragma unroll
            for (int j = 0; j < 4; ++j) {
                const bf16x8 bf = *(const bf16x8*)(bb + ((j * 4 + wave) * 16) * 256 + s * 32);
                acc[j] = __builtin_amdgcn_mfma_f32_16x16x32_bf16(af, bf, acc[j], 0, 0, 0);
            }
        }
        #pragma unroll
        for (int j = 0; j < 4; ++j) {
            const int col = (j * 4 + wave) * 16 + qr;
            const float bo = b_out[col];
            #pragma unroll
            for (int r = 0; r < 4; ++r)
                out[(qbase + quad * 4 + r) * CDIM + col] = acc[j][r] + bo;
        }
    }
}

extern "C" void kernel_launch(void* const* d_in, const int* in_sizes, int n_in,
                              void* d_out, int out_size, void* d_ws, size_t ws_size,
                              hipStream_t stream) {
    const float* query   = (const float*)d_in[0];
    const float* ref_pts = (const float*)d_in[1];
    const float* feat    = (const float*)d_in[2];
    const float* W_off  = (const float*)d_in[5];
    const float* b_off  = (const float*)d_in[6];
    const float* W_attn = (const float*)d_in[7];
    const float* b_attn = (const float*)d_in[8];
    const float* W_out  = (const float*)d_in[9];
    const float* b_out  = (const float*)d_in[10];
    float* out = (float*)d_out;

    const int B = 2;
    const int Len = in_sizes[1] / (B * 2);
    const int rows = B * Len;                     // 43520
    const size_t feat_elems = (size_t)rows * CDIM;

    char* ws = (char*)d_ws;
    short* wt = (short*)ws;                       // 327680 B
    _Float16* feath = (_Float16*)(ws + 327680);   // feat_elems*2
    const size_t need = 327680 + feat_elems * 2;  // ~22.6 MB — keep ws minimal

    if (ws_size >= need) {
        const int n4 = (int)(feat_elems / 4);
        const int fblocks = (n4 + 255) / 256;
        convert_all<<<640 + fblocks, 256, 0, stream>>>(W_off, W_attn, W_out, feat,
                                                       wt, feath, n4);
        msda_gemm1<<<rows / QB, 256, 0, stream>>>(query, wt, b_off, b_attn,
                                                  (char*)out);
        msda_samp2<<<rows / QB, 256, 0, stream>>>(ref_pts, feath, wt, b_out,
                                                  out, Len);
    } else {
        convert_all<<<640, 256, 0, stream>>>(W_off, W_attn, W_out, feat,
                                             wt, (_Float16*)nullptr, 0);
        msda_fused_fb<<<rows / QB, 256, 0, stream>>>(query, ref_pts, feat, wt,
                                                     b_off, b_attn, b_out, out, Len);
    }
}

// Round 10
// 308.266 us; speedup vs baseline: 1.0635x; 1.0635x over previous
//
#include <hip/hip_runtime.h>

// MSDeformAttn — R14: depth-2 pipeline + launch_bounds(256,4) so the allocator
//  can actually grant its registers.
//  R13 post-mortem: at (256,5)/cap-102 the allocator kept its 48-arch target and
//  SERIALIZED the depth-2 pipeline (VGPR=48, zero spill: WRITE=43.5MB pure out),
//  collapsing MLP back to depth-1 + overhead => 118->141us. Lesson: the
//  allocator picks ~half-cap arch targets (R7/R12/R13 all 48 at cap 102);
//  depth-2 needs the cap itself raised. R14 = R13 with samp2 (256,5)->(256,4)
//  (cap 128 -> expect 64-96 arch) + baseL[4] hoist (const-indexed, reg-safe).
//  Trade: ~16 waves/CU (vs 15) x 8 outstanding (vs 4) => ~1.7x MLP.
//  Abort: VGPR=48 again or dur>118us => revert to R12 depth-1, near-roofline.
// B=2, C=256, nH=8, nL=4, nP=4, hd=32, Len=21760.
// Shapes compile-time: [[128,128],[64,64],[32,32],[16,16]], starts [0,16384,20480,21504].

#define NH 8
#define NL 4
#define NP 4
#define CDIM 256
#define HD 32
#define QB 16
#define QSTR 264   // fallback kernel only
#define ASTR 132   // fallback kernel only
// bank swizzle for packed chunk layouts (involution; keyed on bits 4-6)
#define SWZ(c) ((c) ^ ((((c) >> 4)) & 7))

typedef short bf16x8 __attribute__((ext_vector_type(8)));
typedef float f32x4  __attribute__((ext_vector_type(4)));
typedef _Float16 f16x8v __attribute__((ext_vector_type(8)));
typedef _Float16 f16x4v __attribute__((ext_vector_type(4)));
typedef _Float16 f16x2v __attribute__((ext_vector_type(2)));

#define SPLAT8(x) (f16x8v){(x),(x),(x),(x),(x),(x),(x),(x)}

__device__ __forceinline__ short f2bf(float x) {
    union { float f; unsigned u; } v; v.f = x;
    const unsigned r = v.u + 0x7FFFu + ((v.u >> 16) & 1u);
    return (short)(r >> 16);
}

__constant__ int LVL_S_C[4] = {0, 16384, 20480, 21504};

// ---- convert: weights (blocks [0,640)) + features f16 (blocks [640,...)) ----
__global__ __launch_bounds__(256) void convert_all(
    const float* __restrict__ W_off, const float* __restrict__ W_attn,
    const float* __restrict__ W_out, const float* __restrict__ feat,
    short* __restrict__ wt, _Float16* __restrict__ fh, int n4)
{
    const int bid = blockIdx.x;
    if (bid < 640) {
        const int gid = bid * 256 + threadIdx.x;
        if (gid < 65536) {
            const int c = gid >> 8, k = gid & 255;
            wt[gid] = f2bf(W_off[k * 256 + c]);
        } else if (gid < 98304) {
            const int g = gid - 65536, c = g >> 8, k = g & 255;
            wt[gid] = f2bf(W_attn[k * 128 + c]);
        } else if (gid < 163840) {
            const int g = gid - 98304, c = g >> 8, k = g & 255;
            wt[gid] = f2bf(W_out[k * 256 + c]);
        }
    } else {
        const int gid = (bid - 640) * 256 + threadIdx.x;
        if (gid < n4) {
            const float4 v = *(const float4*)&feat[gid * 4];
            f16x4v o;
            o[0] = (_Float16)v.x; o[1] = (_Float16)v.y;
            o[2] = (_Float16)v.z; o[3] = (_Float16)v.w;
            *(f16x4v*)&fh[gid * 4] = o;
        }
    }
}

// ---- kernel B: GEMM1 (MFMA) + softmax; offs/aw (f16) -> out-buffer scratch ----
// scratch layout per global row g (bytes, inside out): [g*1024 + 0, +512) offs
//   f16 [pi*16 + h*2 + xy]; [g*1024 + 512, +768) aw f16 [h*16 + pi].
__global__ __launch_bounds__(256, 4) void msda_gemm1(
    const float* __restrict__ query, const short* __restrict__ wt,
    const float* __restrict__ b_off, const float* __restrict__ b_attn,
    char* __restrict__ scr)
{
    const int t = threadIdx.x;
    const int lane = t & 63;
    const int wave = t >> 6;
    const int qr = lane & 15;
    const int quad = lane >> 4;
    const long long qbase = (long long)blockIdx.x * QB;

    // union (8192 B): qp (bf16, packed lane-linear, SWZ) then offs f16 [i][pi*16+h*2+xy]
    __shared__ __align__(16) short uni[QB * CDIM];
    short* qp = uni;
    _Float16* offs16 = (_Float16*)uni;
    __shared__ __align__(16) _Float16 aw_lds[QB * 128];   // [i][h*16+pi], 4096 B
    // total 12288 B

    // ---- stage query (fp32 -> bf16, packed: chunk = (k>>5)*64 + ((k>>3)&3)*16 + i) ----
    #pragma unroll
    for (int it = 0; it < 4; ++it) {
        const int e = it * 1024 + t * 4;
        const int i = e >> 8, k = e & 255;
        const float4 v = *(const float4*)&query[(qbase + i) * CDIM + k];
        const int chunk = (k >> 5) * 64 + ((k >> 3) & 3) * 16 + i;
        short4 o;
        o.x = f2bf(v.x); o.y = f2bf(v.y); o.z = f2bf(v.z); o.w = f2bf(v.w);
        *(short4*)&qp[SWZ(chunk) * 8 + (k & 7)] = o;
    }
    __syncthreads();

    const short* __restrict__ Wt_off  = wt;
    const short* __restrict__ Wt_attn = wt + 65536;

    {
        f32x4 acc[4], acca[2];
        #pragma unroll
        for (int j = 0; j < 4; ++j) acc[j] = (f32x4){0.f, 0.f, 0.f, 0.f};
        #pragma unroll
        for (int j = 0; j < 2; ++j) acca[j] = (f32x4){0.f, 0.f, 0.f, 0.f};

        const short* bb_off  = Wt_off  + qr * 256 + quad * 8;
        const short* bb_attn = Wt_attn + qr * 256 + quad * 8;
        #pragma unroll
        for (int s = 0; s < 8; ++s) {
            const bf16x8 af = *(const bf16x8*)&qp[SWZ(s * 64 + lane) * 8];  // conflict-free
            #pragma unroll
            for (int j = 0; j < 4; ++j) {
                const bf16x8 bf = *(const bf16x8*)(bb_off + ((j * 4 + wave) * 16) * 256 + s * 32);
                acc[j] = __builtin_amdgcn_mfma_f32_16x16x32_bf16(af, bf, acc[j], 0, 0, 0);
            }
            #pragma unroll
            for (int j = 0; j < 2; ++j) {
                const bf16x8 bf = *(const bf16x8*)(bb_attn + ((j * 4 + wave) * 16) * 256 + s * 32);
                acca[j] = __builtin_amdgcn_mfma_f32_16x16x32_bf16(af, bf, acca[j], 0, 0, 0);
            }
        }
        __syncthreads();   // all qp reads done; union becomes offs16

        // D layout: col = qr, row = quad*4 + r.
        #pragma unroll
        for (int j = 0; j < 4; ++j) {
            const int col = (j * 4 + wave) * 16 + qr;
            const float bo = b_off[col];
            const int h = col >> 5, rem = col & 31;   // rem = pi*2 + xy
            const int pos = (rem >> 1) * 16 + (h << 1) + (rem & 1);
            #pragma unroll
            for (int r = 0; r < 4; ++r)
                offs16[(quad * 4 + r) * 256 + pos] = (_Float16)(acc[j][r] + bo);
        }
        #pragma unroll
        for (int j = 0; j < 2; ++j) {
            const int col = (j * 4 + wave) * 16 + qr;
            const float ba = b_attn[col];
            const int h = col >> 4;                   // pi = col & 15 = qr
            #pragma unroll
            for (int r = 0; r < 4; ++r)
                aw_lds[(quad * 4 + r) * 128 + (h << 4) + qr] = (_Float16)(acca[j][r] + ba);
        }
    }
    __syncthreads();

    // ---- softmax per (row, head), 128 threads, vectorized f16x8 ----
    if (t < QB * NH) {
        const int i = t >> 3, h = t & 7;
        _Float16* row = &aw_lds[i * 128 + (h << 4)];
        f16x8v v0 = *(const f16x8v*)row;
        f16x8v v1 = *(const f16x8v*)(row + 8);
        float vals[16], mx = -1e30f;
        #pragma unroll
        for (int j = 0; j < 8; ++j) { vals[j] = (float)v0[j]; vals[8 + j] = (float)v1[j]; }
        #pragma unroll
        for (int j = 0; j < 16; ++j) mx = fmaxf(mx, vals[j]);
        float s = 0.f;
        #pragma unroll
        for (int j = 0; j < 16; ++j) { vals[j] = __expf(vals[j] - mx); s += vals[j]; }
        const float inv = 1.f / s;
        #pragma unroll
        for (int j = 0; j < 8; ++j) { v0[j] = (_Float16)(vals[j] * inv); v1[j] = (_Float16)(vals[8 + j] * inv); }
        *(f16x8v*)row = v0;
        *(f16x8v*)(row + 8) = v1;
    }
    __syncthreads();

    // ---- bulk copy LDS -> out-scratch (16B chunks, coalesced) ----
    // offs: 16 rows x 512 B = 512 chunks; aw: 16 rows x 256 B = 256 chunks
    #pragma unroll
    for (int it = 0; it < 2; ++it) {
        const int chunk = it * 256 + t;
        const int row = chunk >> 5, c = chunk & 31;
        const bf16x8 v = *(const bf16x8*)&uni[chunk * 8];
        *(bf16x8*)(scr + (qbase + row) * 1024 + c * 16) = v;
    }
    {
        const int row = t >> 4, c = t & 15;
        const bf16x8 v = *(const bf16x8*)&((short*)aw_lds)[t * 8];
        *(bf16x8*)(scr + (qbase + row) * 1024 + 512 + c * 16) = v;
    }
}

// ---- kernel C: stage offs/aw -> LDS, depth-2 pipelined sampler, GEMM2 -> out ----
__global__ __launch_bounds__(256, 4) void msda_samp2(
    const float* __restrict__ ref_pts, const _Float16* __restrict__ feath,
    const short* __restrict__ wt, const float* __restrict__ b_out,
    float* __restrict__ out, int Len)
{
    const int t = threadIdx.x;
    const int lane = t & 63;
    const int wave = t >> 6;
    const int qr = lane & 15;
    const int quad = lane >> 4;

    // ---- bijective XCD swizzle: consecutive final blocks share an XCD's L2.
    int bid;
    {
        const int nwg = gridDim.x, orig = blockIdx.x;
        const int q = nwg >> 3, r = nwg & 7;
        const int xcd = orig & 7, idx = orig >> 3;
        bid = (xcd < r ? xcd * (q + 1) : r * (q + 1) + (xcd - r) * q) + idx;
    }
    const long long qbase = (long long)bid * QB;
    const int b = (int)(qbase / Len);   // Len % QB == 0, no crossing

    // sc: row i at shorts [i*384, i*384+384): offs [0,256), aw [256,384)  (12288 B)
    __shared__ __align__(16) short sc[QB * 384];
    __shared__ __align__(16) short pre_lds[QB * CDIM];  // 8192 B, packed lane-linear, SWZ
    // total 20480 B; (256,4): cap 128 unified — room for depth-2's ~80 arch +
    // 8 AGPR (R13 showed the allocator pins 48 arch at cap 102 and serializes).

    const int rl = t >> 5;
    const float rx0 = ref_pts[(qbase + rl) * 2];
    const float ry0 = ref_pts[(qbase + rl) * 2 + 1];
    const float rx1 = ref_pts[(qbase + 8 + rl) * 2];
    const float ry1 = ref_pts[(qbase + 8 + rl) * 2 + 1];

    // ---- stage scratch rows: 16 rows x 768 B = 768 16B-chunks, 3 iters ----
    const char* scr = (const char*)out;
    #pragma unroll
    for (int it = 0; it < 3; ++it) {
        const int chunk = it * 256 + t;
        const int row = chunk / 48, c = chunk - row * 48;
        const bf16x8 v = *(const bf16x8*)(scr + (qbase + row) * 1024 + c * 16);
        *(bf16x8*)&sc[row * 384 + c * 8] = v;
    }
    __syncthreads();

    // ---- sampling: 2 passes x 8 rows; 32 lanes/row (h = l32>>2, ct = l32&3);
    //      depth-2 software pipeline: 8 outstanding 16B gathers/thread ----
    {
        const int l32 = t & 31;
        const int h = l32 >> 2, ct = l32 & 3;
        const int c0 = h * HD + ct * 8;
        // per-level gather bases (const-indexed after unroll -> registers)
        int baseL[4];
        #pragma unroll
        for (int l = 0; l < 4; ++l) baseL[l] = (b * Len + LVL_S_C[l]) * CDIM + c0;
        #pragma unroll 1
        for (int pass = 0; pass < 2; ++pass) {
            const int i = pass * 8 + rl;
            const float rx = pass ? rx1 : rx0;
            const float ry = pass ? ry1 : ry0;
            const _Float16* __restrict__ offr = (const _Float16*)&sc[i * 384] + h * 2;
            const _Float16* __restrict__ awr  = (const _Float16*)&sc[i * 384 + 256] + h * 16;
            float acc[8];
            #pragma unroll
            for (int c = 0; c < 8; ++c) acc[c] = 0.f;
            f16x8v pA0, pA1, pA2, pA3, pB0, pB1, pB2, pB3;
            float qA0, qA1, qA2, qA3, qB0, qB1, qB2, qB3;

#define MSDA_ISSUE(pi, P0, P1, P2, P3, Q0, Q1, Q2, Q3) do {                         \
            const int l_ = (pi) >> 2;                                               \
            const int Wl_ = 128 >> l_;                                              \
            const int base_ = baseL[l_];                                            \
            const f16x2v oxy_ = *(const f16x2v*)(offr + (pi) * 16);                 \
            const float a_ = (float)awr[(pi)];                                      \
            const float x_ = fmaf(rx, (float)Wl_, (float)oxy_[0]) - 0.5f;           \
            const float y_ = fmaf(ry, (float)Wl_, (float)oxy_[1]) - 0.5f;           \
            const float xf_ = floorf(x_), yf_ = floorf(y_);                         \
            const int x0_ = (int)xf_, y0_ = (int)yf_;                               \
            const float wx_ = x_ - xf_, wy_ = y_ - yf_;                             \
            const float ax0_ = ((unsigned)x0_       < (unsigned)Wl_) ? (1.f - wx_) : 0.f; \
            const float ax1_ = ((unsigned)(x0_ + 1) < (unsigned)Wl_) ? wx_         : 0.f; \
            const float ay0_ = (((unsigned)y0_       < (unsigned)Wl_) ? (1.f - wy_) : 0.f) * a_; \
            const float ay1_ = (((unsigned)(y0_ + 1) < (unsigned)Wl_) ? wy_         : 0.f) * a_; \
            const int x0c_ = min(max(x0_, 0), Wl_ - 1), x1c_ = min(max(x0_ + 1, 0), Wl_ - 1); \
            const int y0c_ = min(max(y0_, 0), Wl_ - 1), y1c_ = min(max(y0_ + 1, 0), Wl_ - 1); \
            P0 = *(const f16x8v*)(feath + base_ + (y0c_ * Wl_ + x0c_) * CDIM);      \
            P1 = *(const f16x8v*)(feath + base_ + (y0c_ * Wl_ + x1c_) * CDIM);      \
            P2 = *(const f16x8v*)(feath + base_ + (y1c_ * Wl_ + x0c_) * CDIM);      \
            P3 = *(const f16x8v*)(feath + base_ + (y1c_ * Wl_ + x1c_) * CDIM);      \
            Q0 = ax0_ * ay0_; Q1 = ax1_ * ay0_;                                     \
            Q2 = ax0_ * ay1_; Q3 = ax1_ * ay1_; } while (0)

#define MSDA_ACCUM(P0, P1, P2, P3, Q0, Q1, Q2, Q3) do {                             \
            f16x8v bil_ = P0 * SPLAT8((_Float16)Q0);                                \
            bil_ += P1 * SPLAT8((_Float16)Q1);                                      \
            bil_ += P2 * SPLAT8((_Float16)Q2);                                      \
            bil_ += P3 * SPLAT8((_Float16)Q3);                                      \
            _Pragma("unroll")                                                       \
            for (int c_ = 0; c_ < 8; ++c_) acc[c_] += (float)bil_[c_]; } while (0)

            MSDA_ISSUE(0, pA0, pA1, pA2, pA3, qA0, qA1, qA2, qA3);
            MSDA_ISSUE(1, pB0, pB1, pB2, pB3, qB0, qB1, qB2, qB3);
            #pragma unroll
            for (int pi = 2; pi < 16; pi += 2) {
                MSDA_ACCUM(pA0, pA1, pA2, pA3, qA0, qA1, qA2, qA3);
                MSDA_ISSUE(pi, pA0, pA1, pA2, pA3, qA0, qA1, qA2, qA3);
                MSDA_ACCUM(pB0, pB1, pB2, pB3, qB0, qB1, qB2, qB3);
                MSDA_ISSUE(pi + 1, pB0, pB1, pB2, pB3, qB0, qB1, qB2, qB3);
            }
            MSDA_ACCUM(pA0, pA1, pA2, pA3, qA0, qA1, qA2, qA3);   // pi = 14
            MSDA_ACCUM(pB0, pB1, pB2, pB3, qB0, qB1, qB2, qB3);   // pi = 15
#undef MSDA_ISSUE
#undef MSDA_ACCUM

            bf16x8 pv;
            #pragma unroll
            for (int c = 0; c < 8; ++c) pv[c] = f2bf(acc[c]);
            // packed lane-linear: chunk = h*64 + ct*16 + i
            *(bf16x8*)&pre_lds[SWZ(h * 64 + ct * 16 + i) * 8] = pv;
        }
    }
    __syncthreads();

    // ---- GEMM2: out = pre @ W_out + b_out; j-loop halved => 8 acc regs peak ----
    {
        const short* bb = wt + 98304 + qr * 256 + quad * 8;
        #pragma unroll 1
        for (int half = 0; half < 2; ++half) {
            f32x4 acc[2];
            #pragma unroll
            for (int j = 0; j < 2; ++j) acc[j] = (f32x4){0.f, 0.f, 0.f, 0.f};
            #pragma unroll
            for (int s = 0; s < 8; ++s) {
                const bf16x8 af = *(const bf16x8*)&pre_lds[SWZ(s * 64 + lane) * 8];
                #pragma unroll
                for (int j = 0; j < 2; ++j) {
                    const int jj = half * 2 + j;
                    const bf16x8 bf = *(const bf16x8*)(bb + ((jj * 4 + wave) * 16) * 256 + s * 32);
                    acc[j] = __builtin_amdgcn_mfma_f32_16x16x32_bf16(af, bf, acc[j], 0, 0, 0);
                }
            }
            #pragma unroll
            for (int j = 0; j < 2; ++j) {
                const int col = ((half * 2 + j) * 4 + wave) * 16 + qr;
                const float bo = b_out[col];
                #pragma unroll
                for (int r = 0; r < 4; ++r)
                    out[(qbase + quad * 4 + r) * CDIM + col] = acc[j][r] + bo;
            }
        }
    }
}

// ---- fallback: fused kernel, fp32 features (ws too small) ----
__global__ __launch_bounds__(256) void msda_fused_fb(
    const float* __restrict__ query, const float* __restrict__ ref_pts,
    const float* __restrict__ feat_f32, const short* __restrict__ wt,
    const float* __restrict__ b_off, const float* __restrict__ b_attn,
    const float* __restrict__ b_out, float* __restrict__ out, int Len)
{
    const int t = threadIdx.x;
    const int lane = t & 63;
    const int wave = t >> 6;
    const int qr = lane & 15;
    const int quad = lane >> 4;
    const long long qbase = (long long)blockIdx.x * QB;
    const int b = (int)(qbase / Len);

    __shared__ __align__(16) char uni[QB * QSTR * 4];
    short* qp = (short*)uni;
    float* offs_lds = (float*)uni;
    __shared__ float aw_lds[QB * ASTR];
    __shared__ __align__(16) short pre_lds[QB * QSTR];
    __shared__ float ref_sm[QB][2];

    #pragma unroll
    for (int it = 0; it < 4; ++it) {
        const int e = it * 1024 + t * 4;
        const int i = e >> 8, k = e & 255;
        const float4 v = *(const float4*)&query[(qbase + i) * CDIM + k];
        short4 o;
        o.x = f2bf(v.x); o.y = f2bf(v.y); o.z = f2bf(v.z); o.w = f2bf(v.w);
        *(short4*)&qp[i * QSTR + k] = o;
    }
    if (t < QB * 2) ref_sm[t >> 1][t & 1] = ref_pts[(qbase + (t >> 1)) * 2 + (t & 1)];
    __syncthreads();

    const short* __restrict__ Wt_off  = wt;
    const short* __restrict__ Wt_attn = wt + 65536;
    const short* __restrict__ Wt_out  = wt + 98304;

    {
        f32x4 acc[4], acca[2];
        #pragma unroll
        for (int j = 0; j < 4; ++j) acc[j] = (f32x4){0.f, 0.f, 0.f, 0.f};
        #pragma unroll
        for (int j = 0; j < 2; ++j) acca[j] = (f32x4){0.f, 0.f, 0.f, 0.f};
        const short* bb_off  = Wt_off  + qr * 256 + quad * 8;
        const short* bb_attn = Wt_attn + qr * 256 + quad * 8;
        #pragma unroll
        for (int s = 0; s < 8; ++s) {
            const bf16x8 af = *(const bf16x8*)&qp[qr * QSTR + s * 32 + quad * 8];
            #pragma unroll
            for (int j = 0; j < 4; ++j) {
                const bf16x8 bf = *(const bf16x8*)(bb_off + ((j * 4 + wave) * 16) * 256 + s * 32);
                acc[j] = __builtin_amdgcn_mfma_f32_16x16x32_bf16(af, bf, acc[j], 0, 0, 0);
            }
            #pragma unroll
            for (int j = 0; j < 2; ++j) {
                const bf16x8 bf = *(const bf16x8*)(bb_attn + ((j * 4 + wave) * 16) * 256 + s * 32);
                acca[j] = __builtin_amdgcn_mfma_f32_16x16x32_bf16(af, bf, acca[j], 0, 0, 0);
            }
        }
        __syncthreads();
        #pragma unroll
        for (int j = 0; j < 4; ++j) {
            const int col = (j * 4 + wave) * 16 + qr;
            const float bo = b_off[col];
            const int h = col >> 5, rem = col & 31;
            #pragma unroll
            for (int r = 0; r < 4; ++r)
                offs_lds[(quad * 4 + r) * QSTR + rem * 8 + h] = acc[j][r] + bo;
        }
        #pragma unroll
        for (int j = 0; j < 2; ++j) {
            const int col = (j * 4 + wave) * 16 + qr;
            const float ba = b_attn[col];
            const int h = col >> 4, rem = col & 15;
            #pragma unroll
            for (int r = 0; r < 4; ++r)
                aw_lds[(quad * 4 + r) * ASTR + rem * 8 + h] = acca[j][r] + ba;
        }
    }
    __syncthreads();

    if (t < QB * NH) {
        const int i = t >> 3, h = t & 7;
        float* row = &aw_lds[i * ASTR];
        float vals[16], mx = -1e30f;
        #pragma unroll
        for (int j = 0; j < 16; ++j) { vals[j] = row[j * 8 + h]; mx = fmaxf(mx, vals[j]); }
        float s = 0.f;
        #pragma unroll
        for (int j = 0; j < 16; ++j) { vals[j] = __expf(vals[j] - mx); s += vals[j]; }
        const float inv = 1.f / s;
        #pragma unroll
        for (int j = 0; j < 16; ++j) row[j * 8 + h] = vals[j] * inv;
    }
    __syncthreads();

    {
        const int rl = t >> 5;
        const int l32 = t & 31;
        const int h = l32 >> 2, ct = l32 & 3;
        const int c0 = h * HD + ct * 8;
        #pragma unroll 1
        for (int pass = 0; pass < 2; ++pass) {
            const int i = pass * 8 + rl;
            const float rx = ref_sm[i][0], ry = ref_sm[i][1];
            const float* __restrict__ offr = &offs_lds[i * QSTR];
            const float* __restrict__ awr  = &aw_lds[i * ASTR];
            float acc[8];
            #pragma unroll
            for (int c = 0; c < 8; ++c) acc[c] = 0.f;
            #pragma unroll
            for (int l = 0; l < NL; ++l) {
                const int Wl = 128 >> l;
                const int base = (b * Len + LVL_S_C[l]) * CDIM + c0;
                #pragma unroll 2
                for (int p = 0; p < NP; ++p) {
                    const int pi = l * 4 + p;
                    const float ox = offr[pi * 16 + h];
                    const float oy = offr[pi * 16 + 8 + h];
                    const float a  = awr[pi * 8 + h];
                    const float x = fmaf(rx, (float)Wl, ox) - 0.5f;
                    const float y = fmaf(ry, (float)Wl, oy) - 0.5f;
                    const float xf = floorf(x), yf = floorf(y);
                    const int x0 = (int)xf, y0 = (int)yf;
                    const float wx = x - xf, wy = y - yf;
                    const float ax0 = ((unsigned)x0       < (unsigned)Wl) ? (1.f - wx) : 0.f;
                    const float ax1 = ((unsigned)(x0 + 1) < (unsigned)Wl) ? wx         : 0.f;
                    const float ay0 = (((unsigned)y0       < (unsigned)Wl) ? (1.f - wy) : 0.f) * a;
                    const float ay1 = (((unsigned)(y0 + 1) < (unsigned)Wl) ? wy         : 0.f) * a;
                    const int x0c = min(max(x0, 0), Wl - 1), x1c = min(max(x0 + 1, 0), Wl - 1);
                    const int y0c = min(max(y0, 0), Wl - 1), y1c = min(max(y0 + 1, 0), Wl - 1);
                    const float w00 = ax0 * ay0, w01 = ax1 * ay0;
                    const float w10 = ax0 * ay1, w11 = ax1 * ay1;
                    const int r0 = base + (y0c * Wl + x0c) * CDIM;
                    const int r1 = base + (y0c * Wl + x1c) * CDIM;
                    const int r2 = base + (y1c * Wl + x0c) * CDIM;
                    const int r3 = base + (y1c * Wl + x1c) * CDIM;
                    f32x4 a0 = *(const f32x4*)(feat_f32 + r0);
                    f32x4 a1 = *(const f32x4*)(feat_f32 + r0 + 4);
                    f32x4 b0 = *(const f32x4*)(feat_f32 + r1);
                    f32x4 b1 = *(const f32x4*)(feat_f32 + r1 + 4);
                    f32x4 c0v = *(const f32x4*)(feat_f32 + r2);
                    f32x4 c1 = *(const f32x4*)(feat_f32 + r2 + 4);
                    f32x4 d0 = *(const f32x4*)(feat_f32 + r3);
                    f32x4 d1 = *(const f32x4*)(feat_f32 + r3 + 4);
                    #pragma unroll
                    for (int c = 0; c < 4; ++c) {
                        acc[c]     += w00*a0[c] + w01*b0[c] + w10*c0v[c] + w11*d0[c];
                        acc[c + 4] += w00*a1[c] + w01*b1[c] + w10*c1[c]  + w11*d1[c];
                    }
                }
            }
            bf16x8 pv;
            #pragma unroll
            for (int c = 0; c < 8; ++c) pv[c] = f2bf(acc[c]);
            *(bf16x8*)&pre_lds[i * QSTR + c0] = pv;
        }
    }
    __syncthreads();

    {
        f32x4 acc[4];
        #pragma unroll
        for (int j = 0; j < 4; ++j) acc[j] = (f32x4){0.f, 0.f, 0.f, 0.f};
        const short* bb = Wt_out + qr * 256 + quad * 8;
        #pragma unroll
        for (int s = 0; s < 8; ++s) {
            const bf16x8 af = *(const bf16x8*)&pre_lds[qr * QSTR + s * 32 + quad * 8];
            #pragma unroll
            for (int j = 0; j < 4; ++j) {
                const bf16x8 bf = *(const bf16x8*)(bb + ((j * 4 + wave) * 16) * 256 + s * 32);
                acc[j] = __builtin_amdgcn_mfma_f32_16x16x32_bf16(af, bf, acc[j], 0, 0, 0);
            }
        }
        #pragma unroll
        for (int j = 0; j < 4; ++j) {
            const int col = (j * 4 + wave) * 16 + qr;
            const float bo = b_out[col];
            #pragma unroll
            for (int r = 0; r < 4; ++r)
                out[(qbase + quad * 4 + r) * CDIM + col] = acc[j][r] + bo;
        }
    }
}

extern "C" void kernel_launch(void* const* d_in, const int* in_sizes, int n_in,
                              void* d_out, int out_size, void* d_ws, size_t ws_size,
                              hipStream_t stream) {
    const float* query   = (const float*)d_in[0];
    const float* ref_pts = (const float*)d_in[1];
    const float* feat    = (const float*)d_in[2];
    const float* W_off  = (const float*)d_in[5];
    const float* b_off  = (const float*)d_in[6];
    const float* W_attn = (const float*)d_in[7];
    const float* b_attn = (const float*)d_in[8];
    const float* W_out  = (const float*)d_in[9];
    const float* b_out  = (const float*)d_in[10];
    float* out = (float*)d_out;

    const int B = 2;
    const int Len = in_sizes[1] / (B * 2);
    const int rows = B * Len;                     // 43520
    const size_t feat_elems = (size_t)rows * CDIM;

    char* ws = (char*)d_ws;
    short* wt = (short*)ws;                       // 327680 B
    _Float16* feath = (_Float16*)(ws + 327680);   // feat_elems*2
    const size_t need = 327680 + feat_elems * 2;  // ~22.6 MB — keep ws minimal

    if (ws_size >= need) {
        const int n4 = (int)(feat_elems / 4);
        const int fblocks = (n4 + 255) / 256;
        convert_all<<<640 + fblocks, 256, 0, stream>>>(W_off, W_attn, W_out, feat,
                                                       wt, feath, n4);
        msda_gemm1<<<rows / QB, 256, 0, stream>>>(query, wt, b_off, b_attn,
                                                  (char*)out);
        msda_samp2<<<rows / QB, 256, 0, stream>>>(ref_pts, feath, wt, b_out,
                                                  out, Len);
    } else {
        convert_all<<<640, 256, 0, stream>>>(W_off, W_attn, W_out, feat,
                                             wt, (_Float16*)nullptr, 0);
        msda_fused_fb<<<rows / QB, 256, 0, stream>>>(query, ref_pts, feat, wt,
                                                     b_off, b_attn, b_out, out, Len);
    }
}

// Round 11
// 291.567 us; speedup vs baseline: 1.1244x; 1.0573x over previous
//
#include <hip/hip_runtime.h>

// MSDeformAttn — R15: samp2 reverted to R12 (depth-1 proven 118us; R13/R14
//  showed the allocator serializes depth-2 at any cap: VGPR 48/56, dur 141/121).
//  NEW finding via cross-round arithmetic: total - samp2 ~ 188us vs round-0's
//  convert+overhead 107us => gemm1 ~= 75-80us — the largest non-samp2 cost.
//  Cause: per-block weight B-reads 192KB x 2720 blocks = 522MB L2 traffic at
//  ~200cy latency, 16 waves/CU. R15 gemm1: QB 16->32 (2 row-tiles per wave,
//  each loaded B-fragment feeds 2 MFMAs; B-traffic halves to 261MB), 48 AGPR +
//  ~35 arch <= cap 102 at (256,5). LDS 24KB -> 5 blocks/CU.
// B=2, C=256, nH=8, nL=4, nP=4, hd=32, Len=21760.
// Shapes compile-time: [[128,128],[64,64],[32,32],[16,16]], starts [0,16384,20480,21504].

#define NH 8
#define NL 4
#define NP 4
#define CDIM 256
#define HD 32
#define QB 16      // samp2 rows/block
#define QBG 32     // gemm1 rows/block
#define QSTR 264   // fallback kernel only
#define ASTR 132   // fallback kernel only
// bank swizzle for packed chunk layouts (involution; keyed on bits 4-6)
#define SWZ(c) ((c) ^ ((((c) >> 4)) & 7))

typedef short bf16x8 __attribute__((ext_vector_type(8)));
typedef float f32x4  __attribute__((ext_vector_type(4)));
typedef _Float16 f16x8v __attribute__((ext_vector_type(8)));
typedef _Float16 f16x4v __attribute__((ext_vector_type(4)));
typedef _Float16 f16x2v __attribute__((ext_vector_type(2)));

#define SPLAT8(x) (f16x8v){(x),(x),(x),(x),(x),(x),(x),(x)}

__device__ __forceinline__ short f2bf(float x) {
    union { float f; unsigned u; } v; v.f = x;
    const unsigned r = v.u + 0x7FFFu + ((v.u >> 16) & 1u);
    return (short)(r >> 16);
}

__constant__ int LVL_S_C[4] = {0, 16384, 20480, 21504};

// ---- convert: weights (blocks [0,640)) + features f16 (blocks [640,...)) ----
__global__ __launch_bounds__(256) void convert_all(
    const float* __restrict__ W_off, const float* __restrict__ W_attn,
    const float* __restrict__ W_out, const float* __restrict__ feat,
    short* __restrict__ wt, _Float16* __restrict__ fh, int n4)
{
    const int bid = blockIdx.x;
    if (bid < 640) {
        const int gid = bid * 256 + threadIdx.x;
        if (gid < 65536) {
            const int c = gid >> 8, k = gid & 255;
            wt[gid] = f2bf(W_off[k * 256 + c]);
        } else if (gid < 98304) {
            const int g = gid - 65536, c = g >> 8, k = g & 255;
            wt[gid] = f2bf(W_attn[k * 128 + c]);
        } else if (gid < 163840) {
            const int g = gid - 98304, c = g >> 8, k = g & 255;
            wt[gid] = f2bf(W_out[k * 256 + c]);
        }
    } else {
        const int gid = (bid - 640) * 256 + threadIdx.x;
        if (gid < n4) {
            const float4 v = *(const float4*)&feat[gid * 4];
            f16x4v o;
            o[0] = (_Float16)v.x; o[1] = (_Float16)v.y;
            o[2] = (_Float16)v.z; o[3] = (_Float16)v.w;
            *(f16x4v*)&fh[gid * 4] = o;
        }
    }
}

// ---- kernel B: GEMM1 (MFMA, 32 rows/block, 2 row-tiles/wave) + softmax ----
// scratch layout per global row g (bytes, inside out): [g*1024 + 0, +512) offs
//   f16 [pi*16 + h*2 + xy]; [g*1024 + 512, +768) aw f16 [h*16 + pi].
__global__ __launch_bounds__(256, 5) void msda_gemm1(
    const float* __restrict__ query, const short* __restrict__ wt,
    const float* __restrict__ b_off, const float* __restrict__ b_attn,
    char* __restrict__ scr)
{
    const int t = threadIdx.x;
    const int lane = t & 63;
    const int wave = t >> 6;
    const int qr = lane & 15;
    const int quad = lane >> 4;
    const long long qbase = (long long)blockIdx.x * QBG;

    // union (16384 B): qp (bf16, 2 groups of 16 rows, packed lane-linear, SWZ
    //   within group; group stride 4096 shorts) then offs f16 [row][pi*16+h*2+xy]
    __shared__ __align__(16) short uni[QBG * CDIM];
    short* qp = uni;
    _Float16* offs16 = (_Float16*)uni;
    __shared__ __align__(16) _Float16 aw_lds[QBG * 128];   // [row][h*16+pi], 8192 B
    // total 24576 B -> 5 blocks/CU at (256,5); 48 AGPR + ~35 arch <= cap 102

    // ---- stage 32 rows (fp32 -> bf16, packed per 16-row group) ----
    #pragma unroll
    for (int it = 0; it < 8; ++it) {
        const int e = it * 1024 + t * 4;
        const int i = e >> 8, k = e & 255;         // i in [0,32)
        const float4 v = *(const float4*)&query[(qbase + i) * CDIM + k];
        const int g = i >> 4, il = i & 15;
        const int chunk = (k >> 5) * 64 + ((k >> 3) & 3) * 16 + il;
        short4 o;
        o.x = f2bf(v.x); o.y = f2bf(v.y); o.z = f2bf(v.z); o.w = f2bf(v.w);
        *(short4*)&qp[g * 4096 + SWZ(chunk) * 8 + (k & 7)] = o;
    }
    __syncthreads();

    const short* __restrict__ Wt_off  = wt;
    const short* __restrict__ Wt_attn = wt + 65536;

    {
        f32x4 acc[2][4], acca[2][2];
        #pragma unroll
        for (int rt = 0; rt < 2; ++rt) {
            #pragma unroll
            for (int j = 0; j < 4; ++j) acc[rt][j] = (f32x4){0.f, 0.f, 0.f, 0.f};
            #pragma unroll
            for (int j = 0; j < 2; ++j) acca[rt][j] = (f32x4){0.f, 0.f, 0.f, 0.f};
        }

        const short* bb_off  = Wt_off  + qr * 256 + quad * 8;
        const short* bb_attn = Wt_attn + qr * 256 + quad * 8;
        #pragma unroll
        for (int s = 0; s < 8; ++s) {
            const bf16x8 af0 = *(const bf16x8*)&qp[SWZ(s * 64 + lane) * 8];
            const bf16x8 af1 = *(const bf16x8*)&qp[4096 + SWZ(s * 64 + lane) * 8];
            #pragma unroll
            for (int j = 0; j < 4; ++j) {
                const bf16x8 bf = *(const bf16x8*)(bb_off + ((j * 4 + wave) * 16) * 256 + s * 32);
                acc[0][j] = __builtin_amdgcn_mfma_f32_16x16x32_bf16(af0, bf, acc[0][j], 0, 0, 0);
                acc[1][j] = __builtin_amdgcn_mfma_f32_16x16x32_bf16(af1, bf, acc[1][j], 0, 0, 0);
            }
            #pragma unroll
            for (int j = 0; j < 2; ++j) {
                const bf16x8 bf = *(const bf16x8*)(bb_attn + ((j * 4 + wave) * 16) * 256 + s * 32);
                acca[0][j] = __builtin_amdgcn_mfma_f32_16x16x32_bf16(af0, bf, acca[0][j], 0, 0, 0);
                acca[1][j] = __builtin_amdgcn_mfma_f32_16x16x32_bf16(af1, bf, acca[1][j], 0, 0, 0);
            }
        }
        __syncthreads();   // all qp reads done; union becomes offs16

        // D layout: col = qr, row = rt*16 + quad*4 + r.
        #pragma unroll
        for (int rt = 0; rt < 2; ++rt) {
            #pragma unroll
            for (int j = 0; j < 4; ++j) {
                const int col = (j * 4 + wave) * 16 + qr;
                const float bo = b_off[col];
                const int h = col >> 5, rem = col & 31;   // rem = pi*2 + xy
                const int pos = (rem >> 1) * 16 + (h << 1) + (rem & 1);
                #pragma unroll
                for (int r = 0; r < 4; ++r)
                    offs16[(rt * 16 + quad * 4 + r) * 256 + pos] = (_Float16)(acc[rt][j][r] + bo);
            }
            #pragma unroll
            for (int j = 0; j < 2; ++j) {
                const int col = (j * 4 + wave) * 16 + qr;
                const float ba = b_attn[col];
                const int h = col >> 4;                   // pi = col & 15 = qr
                #pragma unroll
                for (int r = 0; r < 4; ++r)
                    aw_lds[(rt * 16 + quad * 4 + r) * 128 + (h << 4) + qr] =
                        (_Float16)(acca[rt][j][r] + ba);
            }
        }
    }
    __syncthreads();

    // ---- softmax per (row, head): 32 rows x 8 heads = 256 threads exactly ----
    {
        const int i = t >> 3, h = t & 7;
        _Float16* row = &aw_lds[i * 128 + (h << 4)];
        f16x8v v0 = *(const f16x8v*)row;
        f16x8v v1 = *(const f16x8v*)(row + 8);
        float vals[16], mx = -1e30f;
        #pragma unroll
        for (int j = 0; j < 8; ++j) { vals[j] = (float)v0[j]; vals[8 + j] = (float)v1[j]; }
        #pragma unroll
        for (int j = 0; j < 16; ++j) mx = fmaxf(mx, vals[j]);
        float s = 0.f;
        #pragma unroll
        for (int j = 0; j < 16; ++j) { vals[j] = __expf(vals[j] - mx); s += vals[j]; }
        const float inv = 1.f / s;
        #pragma unroll
        for (int j = 0; j < 8; ++j) { v0[j] = (_Float16)(vals[j] * inv); v1[j] = (_Float16)(vals[8 + j] * inv); }
        *(f16x8v*)row = v0;
        *(f16x8v*)(row + 8) = v1;
    }
    __syncthreads();

    // ---- bulk copy LDS -> out-scratch (16B chunks, coalesced) ----
    // offs: 32 rows x 512 B = 1024 chunks; aw: 32 rows x 256 B = 512 chunks
    #pragma unroll
    for (int it = 0; it < 4; ++it) {
        const int chunk = it * 256 + t;
        const int row = chunk >> 5, c = chunk & 31;
        const bf16x8 v = *(const bf16x8*)&uni[chunk * 8];
        *(bf16x8*)(scr + (qbase + row) * 1024 + c * 16) = v;
    }
    #pragma unroll
    for (int it = 0; it < 2; ++it) {
        const int chunk = it * 256 + t;
        const int row = chunk >> 4, c = chunk & 15;
        const bf16x8 v = *(const bf16x8*)&((short*)aw_lds)[chunk * 8];
        *(bf16x8*)(scr + (qbase + row) * 1024 + 512 + c * 16) = v;
    }
}

// ---- kernel C: stage offs/aw -> LDS, depth-1 sampler, GEMM2 -> out (R12 exact) ----
__global__ __launch_bounds__(256, 5) void msda_samp2(
    const float* __restrict__ ref_pts, const _Float16* __restrict__ feath,
    const short* __restrict__ wt, const float* __restrict__ b_out,
    float* __restrict__ out, int Len)
{
    const int t = threadIdx.x;
    const int lane = t & 63;
    const int wave = t >> 6;
    const int qr = lane & 15;
    const int quad = lane >> 4;

    // ---- bijective XCD swizzle: consecutive final blocks share an XCD's L2.
    int bid;
    {
        const int nwg = gridDim.x, orig = blockIdx.x;
        const int q = nwg >> 3, r = nwg & 7;
        const int xcd = orig & 7, idx = orig >> 3;
        bid = (xcd < r ? xcd * (q + 1) : r * (q + 1) + (xcd - r) * q) + idx;
    }
    const long long qbase = (long long)bid * QB;
    const int b = (int)(qbase / Len);   // Len % QB == 0, no crossing

    // sc: row i at shorts [i*384, i*384+384): offs [0,256), aw [256,384)  (12288 B)
    __shared__ __align__(16) short sc[QB * 384];
    __shared__ __align__(16) short pre_lds[QB * CDIM];  // 8192 B, packed lane-linear, SWZ
    // total 20480 B; (256,5): cap 102 -> 48 arch + 8 AGPR, no spill (R12 proven)

    const int rl = t >> 5;
    const float rx0 = ref_pts[(qbase + rl) * 2];
    const float ry0 = ref_pts[(qbase + rl) * 2 + 1];
    const float rx1 = ref_pts[(qbase + 8 + rl) * 2];
    const float ry1 = ref_pts[(qbase + 8 + rl) * 2 + 1];

    // ---- stage scratch rows: 16 rows x 768 B = 768 16B-chunks, 3 iters ----
    const char* scr = (const char*)out;
    #pragma unroll
    for (int it = 0; it < 3; ++it) {
        const int chunk = it * 256 + t;
        const int row = chunk / 48, c = chunk - row * 48;
        const bf16x8 v = *(const bf16x8*)(scr + (qbase + row) * 1024 + c * 16);
        *(bf16x8*)&sc[row * 384 + c * 8] = v;
    }
    __syncthreads();

    // ---- sampling: 2 passes x 8 rows; 32 lanes/row (h = l32>>2, ct = l32&3) ----
    {
        const int l32 = t & 31;
        const int h = l32 >> 2, ct = l32 & 3;
        const int c0 = h * HD + ct * 8;
        #pragma unroll 1
        for (int pass = 0; pass < 2; ++pass) {
            const int i = pass * 8 + rl;
            const float rx = pass ? rx1 : rx0;
            const float ry = pass ? ry1 : ry0;
            const _Float16* __restrict__ offr = (const _Float16*)&sc[i * 384] + h * 2;
            const _Float16* __restrict__ awr  = (const _Float16*)&sc[i * 384 + 256] + h * 16;
            float acc[8];
            #pragma unroll
            for (int c = 0; c < 8; ++c) acc[c] = 0.f;
            f16x8v p00, p01, p10, p11;
            float q00 = 0.f, q01 = 0.f, q10 = 0.f, q11 = 0.f;
            #pragma unroll
            for (int pi = 0; pi < 16; ++pi) {
                const int l = pi >> 2;
                const int Wl = 128 >> l;
                const int base = (b * Len + LVL_S_C[l]) * CDIM + c0;
                const f16x2v oxy = *(const f16x2v*)(offr + pi * 16);
                const float a = (float)awr[pi];
                const float x = fmaf(rx, (float)Wl, (float)oxy[0]) - 0.5f;
                const float y = fmaf(ry, (float)Wl, (float)oxy[1]) - 0.5f;
                const float xf = floorf(x), yf = floorf(y);
                const int x0 = (int)xf, y0 = (int)yf;
                const float wx = x - xf, wy = y - yf;
                const float ax0 = ((unsigned)x0       < (unsigned)Wl) ? (1.f - wx) : 0.f;
                const float ax1 = ((unsigned)(x0 + 1) < (unsigned)Wl) ? wx         : 0.f;
                const float ay0 = (((unsigned)y0       < (unsigned)Wl) ? (1.f - wy) : 0.f) * a;
                const float ay1 = (((unsigned)(y0 + 1) < (unsigned)Wl) ? wy         : 0.f) * a;
                const int x0c = min(max(x0, 0), Wl - 1), x1c = min(max(x0 + 1, 0), Wl - 1);
                const int y0c = min(max(y0, 0), Wl - 1), y1c = min(max(y0 + 1, 0), Wl - 1);
                const int r00 = base + (y0c * Wl + x0c) * CDIM;
                const int r01 = base + (y0c * Wl + x1c) * CDIM;
                const int r10 = base + (y1c * Wl + x0c) * CDIM;
                const int r11 = base + (y1c * Wl + x1c) * CDIM;
                const f16x8v n00 = *(const f16x8v*)(feath + r00);
                const f16x8v n01 = *(const f16x8v*)(feath + r01);
                const f16x8v n10 = *(const f16x8v*)(feath + r10);
                const f16x8v n11 = *(const f16x8v*)(feath + r11);
                if (pi > 0) {
                    f16x8v bil = p00 * SPLAT8((_Float16)q00);
                    bil += p01 * SPLAT8((_Float16)q01);
                    bil += p10 * SPLAT8((_Float16)q10);
                    bil += p11 * SPLAT8((_Float16)q11);
                    #pragma unroll
                    for (int c = 0; c < 8; ++c) acc[c] += (float)bil[c];
                }
                p00 = n00; p01 = n01; p10 = n10; p11 = n11;
                q00 = ax0 * ay0; q01 = ax1 * ay0; q10 = ax0 * ay1; q11 = ax1 * ay1;
            }
            {   // drain last point
                f16x8v bil = p00 * SPLAT8((_Float16)q00);
                bil += p01 * SPLAT8((_Float16)q01);
                bil += p10 * SPLAT8((_Float16)q10);
                bil += p11 * SPLAT8((_Float16)q11);
                #pragma unroll
                for (int c = 0; c < 8; ++c) acc[c] += (float)bil[c];
            }
            bf16x8 pv;
            #pragma unroll
            for (int c = 0; c < 8; ++c) pv[c] = f2bf(acc[c]);
            // packed lane-linear: chunk = h*64 + ct*16 + i
            *(bf16x8*)&pre_lds[SWZ(h * 64 + ct * 16 + i) * 8] = pv;
        }
    }
    __syncthreads();

    // ---- GEMM2: out = pre @ W_out + b_out; j-loop halved => 8 acc regs peak ----
    {
        const short* bb = wt + 98304 + qr * 256 + quad * 8;
        #pragma unroll 1
        for (int half = 0; half < 2; ++half) {
            f32x4 acc[2];
            #pragma unroll
            for (int j = 0; j < 2; ++j) acc[j] = (f32x4){0.f, 0.f, 0.f, 0.f};
            #pragma unroll
            for (int s = 0; s < 8; ++s) {
                const bf16x8 af = *(const bf16x8*)&pre_lds[SWZ(s * 64 + lane) * 8];
                #pragma unroll
                for (int j = 0; j < 2; ++j) {
                    const int jj = half * 2 + j;
                    const bf16x8 bf = *(const bf16x8*)(bb + ((jj * 4 + wave) * 16) * 256 + s * 32);
                    acc[j] = __builtin_amdgcn_mfma_f32_16x16x32_bf16(af, bf, acc[j], 0, 0, 0);
                }
            }
            #pragma unroll
            for (int j = 0; j < 2; ++j) {
                const int col = ((half * 2 + j) * 4 + wave) * 16 + qr;
                const float bo = b_out[col];
                #pragma unroll
                for (int r = 0; r < 4; ++r)
                    out[(qbase + quad * 4 + r) * CDIM + col] = acc[j][r] + bo;
            }
        }
    }
}

// ---- fallback: fused kernel, fp32 features (ws too small) ----
__global__ __launch_bounds__(256) void msda_fused_fb(
    const float* __restrict__ query, const float* __restrict__ ref_pts,
    const float* __restrict__ feat_f32, const short* __restrict__ wt,
    const float* __restrict__ b_off, const float* __restrict__ b_attn,
    const float* __restrict__ b_out, float* __restrict__ out, int Len)
{
    const int t = threadIdx.x;
    const int lane = t & 63;
    const int wave = t >> 6;
    const int qr = lane & 15;
    const int quad = lane >> 4;
    const long long qbase = (long long)blockIdx.x * QB;
    const int b = (int)(qbase / Len);

    __shared__ __align__(16) char uni[QB * QSTR * 4];
    short* qp = (short*)uni;
    float* offs_lds = (float*)uni;
    __shared__ float aw_lds[QB * ASTR];
    __shared__ __align__(16) short pre_lds[QB * QSTR];
    __shared__ float ref_sm[QB][2];

    #pragma unroll
    for (int it = 0; it < 4; ++it) {
        const int e = it * 1024 + t * 4;
        const int i = e >> 8, k = e & 255;
        const float4 v = *(const float4*)&query[(qbase + i) * CDIM + k];
        short4 o;
        o.x = f2bf(v.x); o.y = f2bf(v.y); o.z = f2bf(v.z); o.w = f2bf(v.w);
        *(short4*)&qp[i * QSTR + k] = o;
    }
    if (t < QB * 2) ref_sm[t >> 1][t & 1] = ref_pts[(qbase + (t >> 1)) * 2 + (t & 1)];
    __syncthreads();

    const short* __restrict__ Wt_off  = wt;
    const short* __restrict__ Wt_attn = wt + 65536;
    const short* __restrict__ Wt_out  = wt + 98304;

    {
        f32x4 acc[4], acca[2];
        #pragma unroll
        for (int j = 0; j < 4; ++j) acc[j] = (f32x4){0.f, 0.f, 0.f, 0.f};
        #pragma unroll
        for (int j = 0; j < 2; ++j) acca[j] = (f32x4){0.f, 0.f, 0.f, 0.f};
        const short* bb_off  = Wt_off  + qr * 256 + quad * 8;
        const short* bb_attn = Wt_attn + qr * 256 + quad * 8;
        #pragma unroll
        for (int s = 0; s < 8; ++s) {
            const bf16x8 af = *(const bf16x8*)&qp[qr * QSTR + s * 32 + quad * 8];
            #pragma unroll
            for (int j = 0; j < 4; ++j) {
                const bf16x8 bf = *(const bf16x8*)(bb_off + ((j * 4 + wave) * 16) * 256 + s * 32);
                acc[j] = __builtin_amdgcn_mfma_f32_16x16x32_bf16(af, bf, acc[j], 0, 0, 0);
            }
            #pragma unroll
            for (int j = 0; j < 2; ++j) {
                const bf16x8 bf = *(const bf16x8*)(bb_attn + ((j * 4 + wave) * 16) * 256 + s * 32);
                acca[j] = __builtin_amdgcn_mfma_f32_16x16x32_bf16(af, bf, acca[j], 0, 0, 0);
            }
        }
        __syncthreads();
        #pragma unroll
        for (int j = 0; j < 4; ++j) {
            const int col = (j * 4 + wave) * 16 + qr;
            const float bo = b_off[col];
            const int h = col >> 5, rem = col & 31;
            #pragma unroll
            for (int r = 0; r < 4; ++r)
                offs_lds[(quad * 4 + r) * QSTR + rem * 8 + h] = acc[j][r] + bo;
        }
        #pragma unroll
        for (int j = 0; j < 2; ++j) {
            const int col = (j * 4 + wave) * 16 + qr;
            const float ba = b_attn[col];
            const int h = col >> 4, rem = col & 15;
            #pragma unroll
            for (int r = 0; r < 4; ++r)
                aw_lds[(quad * 4 + r) * ASTR + rem * 8 + h] = acca[j][r] + ba;
        }
    }
    __syncthreads();

    if (t < QB * NH) {
        const int i = t >> 3, h = t & 7;
        float* row = &aw_lds[i * ASTR];
        float vals[16], mx = -1e30f;
        #pragma unroll
        for (int j = 0; j < 16; ++j) { vals[j] = row[j * 8 + h]; mx = fmaxf(mx, vals[j]); }
        float s = 0.f;
        #pragma unroll
        for (int j = 0; j < 16; ++j) { vals[j] = __expf(vals[j] - mx); s += vals[j]; }
        const float inv = 1.f / s;
        #pragma unroll
        for (int j = 0; j < 16; ++j) row[j * 8 + h] = vals[j] * inv;
    }
    __syncthreads();

    {
        const int rl = t >> 5;
        const int l32 = t & 31;
        const int h = l32 >> 2, ct = l32 & 3;
        const int c0 = h * HD + ct * 8;
        #pragma unroll 1
        for (int pass = 0; pass < 2; ++pass) {
            const int i = pass * 8 + rl;
            const float rx = ref_sm[i][0], ry = ref_sm[i][1];
            const float* __restrict__ offr = &offs_lds[i * QSTR];
            const float* __restrict__ awr  = &aw_lds[i * ASTR];
            float acc[8];
            #pragma unroll
            for (int c = 0; c < 8; ++c) acc[c] = 0.f;
            #pragma unroll
            for (int l = 0; l < NL; ++l) {
                const int Wl = 128 >> l;
                const int base = (b * Len + LVL_S_C[l]) * CDIM + c0;
                #pragma unroll 2
                for (int p = 0; p < NP; ++p) {
                    const int pi = l * 4 + p;
                    const float ox = offr[pi * 16 + h];
                    const float oy = offr[pi * 16 + 8 + h];
                    const float a  = awr[pi * 8 + h];
                    const float x = fmaf(rx, (float)Wl, ox) - 0.5f;
                    const float y = fmaf(ry, (float)Wl, oy) - 0.5f;
                    const float xf = floorf(x), yf = floorf(y);
                    const int x0 = (int)xf, y0 = (int)yf;
                    const float wx = x - xf, wy = y - yf;
                    const float ax0 = ((unsigned)x0       < (unsigned)Wl) ? (1.f - wx) : 0.f;
                    const float ax1 = ((unsigned)(x0 + 1) < (unsigned)Wl) ? wx         : 0.f;
                    const float ay0 = (((unsigned)y0       < (unsigned)Wl) ? (1.f - wy) : 0.f) * a;
                    const float ay1 = (((unsigned)(y0 + 1) < (unsigned)Wl) ? wy         : 0.f) * a;
                    const int x0c = min(max(x0, 0), Wl - 1), x1c = min(max(x0 + 1, 0), Wl - 1);
                    const int y0c = min(max(y0, 0), Wl - 1), y1c = min(max(y0 + 1, 0), Wl - 1);
                    const float w00 = ax0 * ay0, w01 = ax1 * ay0;
                    const float w10 = ax0 * ay1, w11 = ax1 * ay1;
                    const int r0 = base + (y0c * Wl + x0c) * CDIM;
                    const int r1 = base + (y0c * Wl + x1c) * CDIM;
                    const int r2 = base + (y1c * Wl + x0c) * CDIM;
                    const int r3 = base + (y1c * Wl + x1c) * CDIM;
                    f32x4 a0 = *(const f32x4*)(feat_f32 + r0);
                    f32x4 a1 = *(const f32x4*)(feat_f32 + r0 + 4);
                    f32x4 b0 = *(const f32x4*)(feat_f32 + r1);
                    f32x4 b1 = *(const f32x4*)(feat_f32 + r1 + 4);
                    f32x4 c0v = *(const f32x4*)(feat_f32 + r2);
                    f32x4 c1 = *(const f32x4*)(feat_f32 + r2 + 4);
                    f32x4 d0 = *(const f32x4*)(feat_f32 + r3);
                    f32x4 d1 = *(const f32x4*)(feat_f32 + r3 + 4);
                    #pragma unroll
                    for (int c = 0; c < 4; ++c) {
                        acc[c]     += w00*a0[c] + w01*b0[c] + w10*c0v[c] + w11*d0[c];
                        acc[c + 4] += w00*a1[c] + w01*b1[c] + w10*c1[c]  + w11*d1[c];
                    }
                }
            }
            bf16x8 pv;
            #pragma unroll
            for (int c = 0; c < 8; ++c) pv[c] = f2bf(acc[c]);
            *(bf16x8*)&pre_lds[i * QSTR + c0] = pv;
        }
    }
    __syncthreads();

    {
        f32x4 acc[4];
        #pragma unroll
        for (int j = 0; j < 4; ++j) acc[j] = (f32x4){0.f, 0.f, 0.f, 0.f};
        const short* bb = Wt_out + qr * 256 + quad * 8;
        #pragma unroll
        for (int s = 0; s < 8; ++s) {
            const bf16x8 af = *(const bf16x8*)&pre_lds[qr * QSTR + s * 32 + quad * 8];
            #pragma unroll
            for (int j = 0; j < 4; ++j) {
                const bf16x8 bf = *(const bf16x8*)(bb + ((j * 4 + wave) * 16) * 256 + s * 32);
                acc[j] = __builtin_amdgcn_mfma_f32_16x16x32_bf16(af, bf, acc[j], 0, 0, 0);
            }
        }
        #pragma unroll
        for (int j = 0; j < 4; ++j) {
            const int col = (j * 4 + wave) * 16 + qr;
            const float bo = b_out[col];
            #pragma unroll
            for (int r = 0; r < 4; ++r)
                out[(qbase + quad * 4 + r) * CDIM + col] = acc[j][r] + bo;
        }
    }
}

extern "C" void kernel_launch(void* const* d_in, const int* in_sizes, int n_in,
                              void* d_out, int out_size, void* d_ws, size_t ws_size,
                              hipStream_t stream) {
    const float* query   = (const float*)d_in[0];
    const float* ref_pts = (const float*)d_in[1];
    const float* feat    = (const float*)d_in[2];
    const float* W_off  = (const float*)d_in[5];
    const float* b_off  = (const float*)d_in[6];
    const float* W_attn = (const float*)d_in[7];
    const float* b_attn = (const float*)d_in[8];
    const float* W_out  = (const float*)d_in[9];
    const float* b_out  = (const float*)d_in[10];
    float* out = (float*)d_out;

    const int B = 2;
    const int Len = in_sizes[1] / (B * 2);
    const int rows = B * Len;                     // 43520
    const size_t feat_elems = (size_t)rows * CDIM;

    char* ws = (char*)d_ws;
    short* wt = (short*)ws;                       // 327680 B
    _Float16* feath = (_Float16*)(ws + 327680);   // feat_elems*2
    const size_t need = 327680 + feat_elems * 2;  // ~22.6 MB — keep ws minimal

    if (ws_size >= need) {
        const int n4 = (int)(feat_elems / 4);
        const int fblocks = (n4 + 255) / 256;
        convert_all<<<640 + fblocks, 256, 0, stream>>>(W_off, W_attn, W_out, feat,
                                                       wt, feath, n4);
        msda_gemm1<<<rows / QBG, 256, 0, stream>>>(query, wt, b_off, b_attn,
                                                   (char*)out);
        msda_samp2<<<rows / QB, 256, 0, stream>>>(ref_pts, feath, wt, b_out,
                                                  out, Len);
    } else {
        convert_all<<<640, 256, 0, stream>>>(W_off, W_attn, W_out, feat,
                                             wt, (_Float16*)nullptr, 0);
        msda_fused_fb<<<rows / QB, 256, 0, stream>>>(query, ref_pts, feat, wt,
                                                     b_off, b_attn, b_out, out, Len);
    }
}